// Round 1
// baseline (399.473 us; speedup 1.0000x reference)
//
#include <hip/hip_runtime.h>

// Problem constants
#define BB   8
#define CIN  128
#define COUT 128
#define KS   7
#define HH   32
#define WWID 32
#define HW   1024
#define NG   8     // dynamic-weight groups
#define GC   16    // channels per group
#define MROWS 768  // 256 t-rows + 512 v-rows
#define KDIM 512
#define WMAP_O 392 // 49*8
#define C2K  64

// ---------------------------------------------------------------- lift
__global__ __launch_bounds__(256) void lift_kernel(
    const float* __restrict__ v_w, const float* __restrict__ c1_w,
    float* __restrict__ Wcat)
{
    int idx = blockIdx.x * 256 + threadIdx.x;
    if (idx >= MROWS * KDIM) return;
    int row = idx >> 9;          // /512
    int col = idx & 511;
    int i = col >> 2, s = col & 3;
    float val;
    if (row < 256) {
        int o = row >> 2, r = row & 3;
        val = c1_w[(o * CIN + i) * 4 + ((s - r) & 3)];
    } else {
        int ro = row - 256;
        int o = ro >> 2, r = ro & 3;
        val = v_w[(o * CIN + i) * 4 + ((s - r) & 3)];
    }
    Wcat[idx] = val;
}

// ---------------------------------------------------------------- gemm1: tcat[b] = Wcat @ x[b]
#define BM 64
#define BN 64
#define BKK 16
__global__ __launch_bounds__(256) void gemm1_kernel(
    const float* __restrict__ Wcat, const float* __restrict__ x,
    float* __restrict__ tcat)
{
    __shared__ float As[BKK][BM + 1];
    __shared__ float Bs[BKK][BN + 1];
    int b  = blockIdx.z;
    int m0 = blockIdx.y * BM;
    int n0 = blockIdx.x * BN;
    const float* Xb = x + (size_t)b * KDIM * HW;
    float* Cb = tcat + (size_t)b * MROWS * HW;
    int tid = threadIdx.x;
    int tx = tid & 15, ty = tid >> 4;
    float acc[4][4] = {};
    for (int k0 = 0; k0 < KDIM; k0 += BKK) {
        #pragma unroll
        for (int l = 0; l < 4; ++l) {
            int flat = l * 256 + tid;
            int m = flat >> 4, k = flat & 15;
            As[k][m] = Wcat[(size_t)(m0 + m) * KDIM + k0 + k];
        }
        #pragma unroll
        for (int l = 0; l < 4; ++l) {
            int flat = l * 256 + tid;
            int k = flat >> 6, n = flat & 63;
            Bs[k][n] = Xb[(size_t)(k0 + k) * HW + n0 + n];
        }
        __syncthreads();
        #pragma unroll
        for (int k = 0; k < BKK; ++k) {
            float a[4], bv[4];
            #pragma unroll
            for (int i = 0; i < 4; ++i) a[i] = As[k][ty * 4 + i];
            #pragma unroll
            for (int j = 0; j < 4; ++j) bv[j] = Bs[k][tx * 4 + j];
            #pragma unroll
            for (int i = 0; i < 4; ++i)
                #pragma unroll
                for (int j = 0; j < 4; ++j)
                    acc[i][j] += a[i] * bv[j];
        }
        __syncthreads();
    }
    #pragma unroll
    for (int i = 0; i < 4; ++i) {
        int m = m0 + ty * 4 + i;
        #pragma unroll
        for (int j = 0; j < 4; ++j)
            Cb[(size_t)m * HW + n0 + tx * 4 + j] = acc[i][j];
    }
}

// ---------------------------------------------------------------- GroupNorm(64 groups of 4ch) + affine + ReLU, in place on t rows
__global__ __launch_bounds__(256) void gn_kernel(
    float* __restrict__ tcat,
    const float* __restrict__ gn_g, const float* __restrict__ gn_b)
{
    int blk = blockIdx.x;            // b*64 + c64
    int b = blk >> 6, c64 = blk & 63;
    float* base = tcat + ((size_t)b * MROWS + c64 * 4) * HW;
    int tid = threadIdx.x;
    float s = 0.f, sq = 0.f;
    for (int i = tid; i < 4096; i += 256) {
        float v = base[i];
        s += v; sq += v * v;
    }
    __shared__ float rs[4], rq[4];
    int lane = tid & 63, wv = tid >> 6;
    #pragma unroll
    for (int off = 32; off; off >>= 1) {
        s  += __shfl_down(s, off);
        sq += __shfl_down(sq, off);
    }
    if (lane == 0) { rs[wv] = s; rq[wv] = sq; }
    __syncthreads();
    if (tid == 0) {
        float ts = rs[0] + rs[1] + rs[2] + rs[3];
        float tq = rq[0] + rq[1] + rq[2] + rq[3];
        float mu = ts * (1.f / 4096.f);
        float var = tq * (1.f / 4096.f) - mu * mu;
        rs[0] = mu;
        rq[0] = rsqrtf(var + 1e-5f);
    }
    __syncthreads();
    float mu = rs[0], inv = rq[0];
    for (int i = tid; i < 4096; i += 256) {
        int cc = i >> 10;            // local channel 0..3
        int ch = c64 * 4 + cc;
        float v = (base[i] - mu) * inv;
        v = v * gn_g[ch] + gn_b[ch];
        base[i] = fmaxf(v, 0.f);
    }
}

// ---------------------------------------------------------------- wmap[b,r,o,hw] = c2_w[o,:] . t[b, :*4+r, hw] + c2_b[o]
#define WT 128
__global__ __launch_bounds__(256) void wmap_kernel(
    const float* __restrict__ tcat, const float* __restrict__ c2_w,
    const float* __restrict__ c2_b, float* __restrict__ wmap)
{
    int bx = blockIdx.x;             // b*4 + r
    int b = bx >> 2, r = bx & 3;
    int hw0 = blockIdx.y * WT;
    __shared__ float ts[C2K][WT];
    int tid = threadIdx.x;
    #pragma unroll
    for (int l = 0; l < (C2K * WT) / 256; ++l) {
        int flat = l * 256 + tid;
        int c = flat >> 7, hw = flat & 127;
        ts[c][hw] = tcat[((size_t)b * MROWS + c * 4 + r) * HW + hw0 + hw];
    }
    __syncthreads();
    int hwl   = tid & 127;
    int ohalf = tid >> 7;            // 0 or 1
    float* wb = wmap + (size_t)(b * 4 + r) * WMAP_O * HW + hw0 + hwl;
    for (int o = ohalf * 196; o < ohalf * 196 + 196; ++o) {
        float acc = c2_b[o];
        const float* wrow = c2_w + (size_t)o * C2K;
        #pragma unroll 8
        for (int c = 0; c < C2K; ++c) acc += wrow[c] * ts[c][hwl];
        wb[(size_t)o * HW] = acc;
    }
}

// ---------------------------------------------------------------- aggregation with kernel rotation
__global__ __launch_bounds__(256) void agg_kernel(
    const float* __restrict__ tcat, const float* __restrict__ wmap,
    float* __restrict__ out)
{
    int bx = blockIdx.x;             // b*32 + g*4 + r
    int b = bx >> 5;
    int g = (bx >> 2) & 7;
    int r = bx & 3;
    int h0 = blockIdx.y * 8;
    int tid = threadIdx.x;
    int tw = tid & 31, th = tid >> 5;
    int h = h0 + th, w = tw;

    // rotated-kernel index map: orig_idx = A + Bc*ki + Cc*kj  (block-uniform)
    int A, Bc, Cc;
    if      (r == 0) { A = 0;  Bc = 7;  Cc = 1;  }
    else if (r == 1) { A = 6;  Bc = -1; Cc = 7;  }
    else if (r == 2) { A = 48; Bc = -7; Cc = -1; }
    else             { A = 42; Bc = 1;  Cc = -7; }

    float wr[49];
    const float* wmb = wmap + (size_t)(b * 4 + r) * WMAP_O * HW + h * WWID + w;
    #pragma unroll
    for (int p = 0; p < 49; ++p) {
        int ki = p / 7, kj = p % 7;
        wr[p] = wmb[(size_t)(g * 49 + A + Bc * ki + Cc * kj) * HW];
    }

    __shared__ float vt[14][40];
    const float* vbase = tcat + ((size_t)b * MROWS + 256) * HW;  // v rows
    for (int c = 0; c < GC; ++c) {
        int ch = (g * GC + c) * 4 + r;
        __syncthreads();
        for (int idx = tid; idx < 14 * 38; idx += 256) {
            int row = idx / 38, col = idx % 38;
            int gh = h0 - 3 + row, gw = col - 3;
            float v = 0.f;
            if (gh >= 0 && gh < HH && gw >= 0 && gw < WWID)
                v = vbase[(size_t)ch * HW + gh * WWID + gw];
            vt[row][col] = v;
        }
        __syncthreads();
        float acc = 0.f;
        #pragma unroll
        for (int p = 0; p < 49; ++p)
            acc += wr[p] * vt[th + p / 7][tw + p % 7];
        out[((size_t)b * 512 + ch) * HW + h * WWID + w] = acc;
    }
}

// ---------------------------------------------------------------- launch
extern "C" void kernel_launch(void* const* d_in, const int* in_sizes, int n_in,
                              void* d_out, int out_size, void* d_ws, size_t ws_size,
                              hipStream_t stream)
{
    const float* x    = (const float*)d_in[0];
    const float* v_w  = (const float*)d_in[1];
    const float* c1_w = (const float*)d_in[2];
    const float* gn_g = (const float*)d_in[3];
    const float* gn_b = (const float*)d_in[4];
    const float* c2_w = (const float*)d_in[5];
    const float* c2_b = (const float*)d_in[6];
    float* out = (float*)d_out;

    float* ws   = (float*)d_ws;
    float* Wcat = ws;                                  // 768*512            = 0.39M floats
    float* tcat = Wcat + (size_t)MROWS * KDIM;         // 8*768*1024         = 6.29M floats
    float* wmap = tcat + (size_t)BB * MROWS * HW;      // 8*4*392*1024       = 12.85M floats
                                                       // total ~78 MB

    lift_kernel <<<(MROWS * KDIM + 255) / 256, 256, 0, stream>>>(v_w, c1_w, Wcat);
    gemm1_kernel<<<dim3(HW / BN, MROWS / BM, BB), 256, 0, stream>>>(Wcat, x, tcat);
    gn_kernel   <<<BB * 64, 256, 0, stream>>>(tcat, gn_g, gn_b);
    wmap_kernel <<<dim3(BB * 4, HW / WT), 256, 0, stream>>>(tcat, c2_w, c2_b, wmap);
    agg_kernel  <<<dim3(BB * NG * 4, 4), 256, 0, stream>>>(tcat, wmap, out);
}

// Round 2
// 225.821 us; speedup vs baseline: 1.7690x; 1.7690x over previous
//
#include <hip/hip_runtime.h>

// Problem constants
#define BB   8
#define CIN  128
#define COUT 128
#define KS   7
#define HH   32
#define WWID 32
#define HW   1024
#define NG   8     // dynamic-weight groups
#define GC   16    // channels per group
#define MROWS 768  // 256 t-rows + 512 v-rows
#define KDIM 512
#define WMAP_O 392 // 49*8
#define C2K  64

// ---------------------------------------------------------------- lift
__global__ __launch_bounds__(256) void lift_kernel(
    const float* __restrict__ v_w, const float* __restrict__ c1_w,
    float* __restrict__ Wcat)
{
    int idx = blockIdx.x * 256 + threadIdx.x;
    if (idx >= MROWS * KDIM) return;
    int row = idx >> 9;          // /512
    int col = idx & 511;
    int i = col >> 2, s = col & 3;
    float val;
    if (row < 256) {
        int o = row >> 2, r = row & 3;
        val = c1_w[(o * CIN + i) * 4 + ((s - r) & 3)];
    } else {
        int ro = row - 256;
        int o = ro >> 2, r = ro & 3;
        val = v_w[(o * CIN + i) * 4 + ((s - r) & 3)];
    }
    Wcat[idx] = val;
}

// ---------------------------------------------------------------- gemm1: tcat[b] = Wcat @ x[b]
#define BM 64
#define BN 64
#define BKK 16
__global__ __launch_bounds__(256) void gemm1_kernel(
    const float* __restrict__ Wcat, const float* __restrict__ x,
    float* __restrict__ tcat)
{
    __shared__ float As[BKK][BM + 1];
    __shared__ float Bs[BKK][BN + 1];
    int b  = blockIdx.z;
    int m0 = blockIdx.y * BM;
    int n0 = blockIdx.x * BN;
    const float* Xb = x + (size_t)b * KDIM * HW;
    float* Cb = tcat + (size_t)b * MROWS * HW;
    int tid = threadIdx.x;
    int tx = tid & 15, ty = tid >> 4;
    float acc[4][4] = {};
    for (int k0 = 0; k0 < KDIM; k0 += BKK) {
        #pragma unroll
        for (int l = 0; l < 4; ++l) {
            int flat = l * 256 + tid;
            int m = flat >> 4, k = flat & 15;
            As[k][m] = Wcat[(size_t)(m0 + m) * KDIM + k0 + k];
        }
        #pragma unroll
        for (int l = 0; l < 4; ++l) {
            int flat = l * 256 + tid;
            int k = flat >> 6, n = flat & 63;
            Bs[k][n] = Xb[(size_t)(k0 + k) * HW + n0 + n];
        }
        __syncthreads();
        #pragma unroll
        for (int k = 0; k < BKK; ++k) {
            float a[4], bv[4];
            #pragma unroll
            for (int i = 0; i < 4; ++i) a[i] = As[k][ty * 4 + i];
            #pragma unroll
            for (int j = 0; j < 4; ++j) bv[j] = Bs[k][tx * 4 + j];
            #pragma unroll
            for (int i = 0; i < 4; ++i)
                #pragma unroll
                for (int j = 0; j < 4; ++j)
                    acc[i][j] += a[i] * bv[j];
        }
        __syncthreads();
    }
    #pragma unroll
    for (int i = 0; i < 4; ++i) {
        int m = m0 + ty * 4 + i;
        #pragma unroll
        for (int j = 0; j < 4; ++j)
            Cb[(size_t)m * HW + n0 + tx * 4 + j] = acc[i][j];
    }
}

// ---------------------------------------------------------------- GroupNorm(64 groups of 4ch) + affine + ReLU, in place on t rows
__global__ __launch_bounds__(256) void gn_kernel(
    float* __restrict__ tcat,
    const float* __restrict__ gn_g, const float* __restrict__ gn_b)
{
    int blk = blockIdx.x;            // b*64 + c64
    int b = blk >> 6, c64 = blk & 63;
    float* base = tcat + ((size_t)b * MROWS + c64 * 4) * HW;
    int tid = threadIdx.x;
    float s = 0.f, sq = 0.f;
    for (int i = tid; i < 4096; i += 256) {
        float v = base[i];
        s += v; sq += v * v;
    }
    __shared__ float rs[4], rq[4];
    int lane = tid & 63, wv = tid >> 6;
    #pragma unroll
    for (int off = 32; off; off >>= 1) {
        s  += __shfl_down(s, off);
        sq += __shfl_down(sq, off);
    }
    if (lane == 0) { rs[wv] = s; rq[wv] = sq; }
    __syncthreads();
    if (tid == 0) {
        float ts = rs[0] + rs[1] + rs[2] + rs[3];
        float tq = rq[0] + rq[1] + rq[2] + rq[3];
        float mu = ts * (1.f / 4096.f);
        float var = tq * (1.f / 4096.f) - mu * mu;
        rs[0] = mu;
        rq[0] = rsqrtf(var + 1e-5f);
    }
    __syncthreads();
    float mu = rs[0], inv = rq[0];
    for (int i = tid; i < 4096; i += 256) {
        int cc = i >> 10;            // local channel 0..3
        int ch = c64 * 4 + cc;
        float v = (base[i] - mu) * inv;
        v = v * gn_g[ch] + gn_b[ch];
        base[i] = fmaxf(v, 0.f);
    }
}

// ---------------------------------------------------------------- wmap v2: tiled GEMM
// wmap[(b*4+r), o, hw] = c2_b[o] + sum_c c2_w[o,c] * tcat[b, c*4+r, hw]
#define WO  56   // o-tile (392 = 7*56)
#define WHW 128  // hw-tile
__global__ __launch_bounds__(256) void wmap2_kernel(
    const float* __restrict__ tcat, const float* __restrict__ c2_w,
    const float* __restrict__ c2_b, float* __restrict__ wmap)
{
    __shared__ float ts[C2K][WHW];   // 32 KB
    __shared__ float ws[WO][C2K];    // 14 KB
    int bx = blockIdx.x;             // b*4 + r
    int b = bx >> 2, r = bx & 3;
    int hw0 = blockIdx.y * WHW;
    int o0  = blockIdx.z * WO;
    int tid = threadIdx.x;
    // stage t-tile (coalesced over hw)
    #pragma unroll
    for (int l = 0; l < (C2K * WHW) / 256; ++l) {
        int flat = l * 256 + tid;
        int c = flat >> 7, hw = flat & 127;
        ts[c][hw] = tcat[((size_t)b * MROWS + c * 4 + r) * HW + hw0 + hw];
    }
    // stage weight tile
    for (int flat = tid; flat < WO * C2K; flat += 256) {
        int o = flat >> 6, k = flat & 63;
        ws[o][k] = c2_w[(size_t)(o0 + o) * C2K + k];
    }
    __syncthreads();
    int hwl = tid & 63;              // hw lane (covers hwl and hwl+64)
    int oq  = tid >> 6;              // 0..3, each owns 14 o-rows
    float acc[14][2];
    #pragma unroll
    for (int i = 0; i < 14; ++i) {
        float bv = c2_b[o0 + oq * 14 + i];
        acc[i][0] = bv; acc[i][1] = bv;
    }
    for (int k = 0; k < C2K; ++k) {
        float t0 = ts[k][hwl], t1 = ts[k][hwl + 64];
        #pragma unroll
        for (int i = 0; i < 14; ++i) {
            float wv = ws[oq * 14 + i][k];   // wave-uniform -> LDS broadcast
            acc[i][0] += wv * t0;
            acc[i][1] += wv * t1;
        }
    }
    float* wb = wmap + (size_t)bx * WMAP_O * HW + hw0;
    #pragma unroll
    for (int i = 0; i < 14; ++i) {
        int o = o0 + oq * 14 + i;
        wb[(size_t)o * HW + hwl]      = acc[i][0];
        wb[(size_t)o * HW + hwl + 64] = acc[i][1];
    }
}

// ---------------------------------------------------------------- aggregation with kernel rotation
__global__ __launch_bounds__(256) void agg_kernel(
    const float* __restrict__ tcat, const float* __restrict__ wmap,
    float* __restrict__ out)
{
    int bx = blockIdx.x;             // b*32 + g*4 + r
    int b = bx >> 5;
    int g = (bx >> 2) & 7;
    int r = bx & 3;
    int h0 = blockIdx.y * 8;
    int tid = threadIdx.x;
    int tw = tid & 31, th = tid >> 5;
    int h = h0 + th, w = tw;

    // rotated-kernel index map: orig_idx = A + Bc*ki + Cc*kj  (block-uniform)
    int A, Bc, Cc;
    if      (r == 0) { A = 0;  Bc = 7;  Cc = 1;  }
    else if (r == 1) { A = 6;  Bc = -1; Cc = 7;  }
    else if (r == 2) { A = 48; Bc = -7; Cc = -1; }
    else             { A = 42; Bc = 1;  Cc = -7; }

    float wr[49];
    const float* wmb = wmap + (size_t)(b * 4 + r) * WMAP_O * HW + h * WWID + w;
    #pragma unroll
    for (int p = 0; p < 49; ++p) {
        int ki = p / 7, kj = p % 7;
        wr[p] = wmb[(size_t)(g * 49 + A + Bc * ki + Cc * kj) * HW];
    }

    __shared__ float vt[14][40];
    const float* vbase = tcat + ((size_t)b * MROWS + 256) * HW;  // v rows
    for (int c = 0; c < GC; ++c) {
        int ch = (g * GC + c) * 4 + r;
        __syncthreads();
        for (int idx = tid; idx < 14 * 38; idx += 256) {
            int row = idx / 38, col = idx % 38;
            int gh = h0 - 3 + row, gw = col - 3;
            float v = 0.f;
            if (gh >= 0 && gh < HH && gw >= 0 && gw < WWID)
                v = vbase[(size_t)ch * HW + gh * WWID + gw];
            vt[row][col] = v;
        }
        __syncthreads();
        float acc = 0.f;
        #pragma unroll
        for (int p = 0; p < 49; ++p)
            acc += wr[p] * vt[th + p / 7][tw + p % 7];
        out[((size_t)b * 512 + ch) * HW + h * WWID + w] = acc;
    }
}

// ---------------------------------------------------------------- launch
extern "C" void kernel_launch(void* const* d_in, const int* in_sizes, int n_in,
                              void* d_out, int out_size, void* d_ws, size_t ws_size,
                              hipStream_t stream)
{
    const float* x    = (const float*)d_in[0];
    const float* v_w  = (const float*)d_in[1];
    const float* c1_w = (const float*)d_in[2];
    const float* gn_g = (const float*)d_in[3];
    const float* gn_b = (const float*)d_in[4];
    const float* c2_w = (const float*)d_in[5];
    const float* c2_b = (const float*)d_in[6];
    float* out = (float*)d_out;

    float* ws   = (float*)d_ws;
    float* Wcat = ws;                                  // 768*512            = 0.39M floats
    float* tcat = Wcat + (size_t)MROWS * KDIM;         // 8*768*1024         = 6.29M floats
    float* wmap = tcat + (size_t)BB * MROWS * HW;      // 8*4*392*1024       = 12.85M floats
                                                       // total ~78 MB

    lift_kernel <<<(MROWS * KDIM + 255) / 256, 256, 0, stream>>>(v_w, c1_w, Wcat);
    gemm1_kernel<<<dim3(HW / BN, MROWS / BM, BB), 256, 0, stream>>>(Wcat, x, tcat);
    gn_kernel   <<<BB * 64, 256, 0, stream>>>(tcat, gn_g, gn_b);
    wmap2_kernel<<<dim3(BB * 4, HW / WHW, WMAP_O / WO), 256, 0, stream>>>(tcat, c2_w, c2_b, wmap);
    agg_kernel  <<<dim3(BB * NG * 4, 4), 256, 0, stream>>>(tcat, wmap, out);
}

// Round 3
// 108.547 us; speedup vs baseline: 3.6802x; 2.0804x over previous
//
#include <hip/hip_runtime.h>

// Problem constants
#define BB   8
#define CIN  128
#define COUT 128
#define KS   7
#define HH   32
#define WWID 32
#define HW   1024
#define NG   8     // dynamic-weight groups
#define GC   16    // channels per group
#define MROWS 768  // 256 t-rows + 512 v-rows
#define KDIM 512
#define WMAP_O 392 // 49*8
#define C2K  64

typedef __attribute__((ext_vector_type(8))) short bf16x8;
typedef __attribute__((ext_vector_type(4))) float f32x4;

__device__ __forceinline__ short f2bf(float f) {
    unsigned u = __builtin_bit_cast(unsigned, f);
    u += 0x7fff + ((u >> 16) & 1);   // RNE
    return (short)(u >> 16);
}

// ---------------------------------------------------------------- lift (bf16 out)
__global__ __launch_bounds__(256) void lift_bf16_kernel(
    const float* __restrict__ v_w, const float* __restrict__ c1_w,
    short* __restrict__ Wb)
{
    int idx = blockIdx.x * 256 + threadIdx.x;
    if (idx >= MROWS * KDIM) return;
    int row = idx >> 9;          // /512
    int col = idx & 511;
    int i = col >> 2, s = col & 3;
    float val;
    if (row < 256) {
        int o = row >> 2, r = row & 3;
        val = c1_w[(o * CIN + i) * 4 + ((s - r) & 3)];
    } else {
        int ro = row - 256;
        int o = ro >> 2, r = ro & 3;
        val = v_w[(o * CIN + i) * 4 + ((s - r) & 3)];
    }
    Wb[idx] = f2bf(val);
}

// ---------------------------------------------------------------- transpose x -> XT bf16 [b][hw][c]
__global__ __launch_bounds__(256) void xt_kernel(
    const float* __restrict__ x, short* __restrict__ XT)
{
    __shared__ short t[64][66];
    int b = blockIdx.z, c0 = blockIdx.y * 64, n0 = blockIdx.x * 64;
    int tid = threadIdx.x;
    const float* xb = x + ((size_t)b * KDIM + c0) * HW + n0;
    #pragma unroll
    for (int l = 0; l < 16; ++l) {
        int flat = l * 256 + tid;
        int row = flat >> 6, col = flat & 63;   // row=c_local, col=n_local
        t[col][row] = f2bf(xb[(size_t)row * HW + col]);
    }
    __syncthreads();
    short* xt = XT + ((size_t)b * HW + n0) * KDIM + c0;
    #pragma unroll
    for (int l = 0; l < 8; ++l) {
        int u = l * 256 + tid;
        int nrow = u >> 5, cp = (u & 31) * 2;
        short2 v = make_short2(t[nrow][cp], t[nrow][cp + 1]);
        *(short2*)(xt + (size_t)nrow * KDIM + cp) = v;
    }
}

// ---------------------------------------------------------------- MFMA GEMM: tcat[b] = Wb @ X[b]
// A = Wb [768][512] bf16, B^T = XT [b][1024][512] bf16, C = tcat fp32
#define GBM 64
#define GBN 128
__global__ __launch_bounds__(256) void gemm_mfma_kernel(
    const short* __restrict__ Wb, const short* __restrict__ XT,
    float* __restrict__ tcat)
{
    __shared__ short As[GBM * 32];   // 4 KB
    __shared__ short Bs[GBN * 32];   // 8 KB
    int b  = blockIdx.z;
    int m0 = blockIdx.y * GBM;
    int n0 = blockIdx.x * GBN;
    int tid = threadIdx.x;
    int lane = tid & 63, wv = tid >> 6;
    int wm = wv & 1, wn = wv >> 1;          // wave tile: 32 rows x 64 cols
    int rl = lane & 15, kg = lane >> 4;
    const short* Ab = Wb + (size_t)m0 * KDIM;
    const short* Bb = XT + ((size_t)b * HW + n0) * KDIM;
    f32x4 acc[2][4] = {};

    for (int k0 = 0; k0 < KDIM; k0 += 32) {
        // stage A: 64 rows x 4 chunks(16B) = 256 chunks, 1 per thread
        {
            int c = tid;
            int row = c >> 2, kc = c & 3;
            __builtin_amdgcn_global_load_lds(
                (const __attribute__((address_space(1))) void*)(Ab + (size_t)row * KDIM + k0 + kc * 8),
                (__attribute__((address_space(3))) void*)(As + wv * 512),
                16, 0, 0);
        }
        // stage B: 128 rows x 4 chunks = 512 chunks, 2 per thread
        #pragma unroll
        for (int l = 0; l < 2; ++l) {
            int c = l * 256 + tid;
            int row = c >> 2, kc = c & 3;
            __builtin_amdgcn_global_load_lds(
                (const __attribute__((address_space(1))) void*)(Bb + (size_t)row * KDIM + k0 + kc * 8),
                (__attribute__((address_space(3))) void*)(Bs + (l * 256 + wv * 64) * 8),
                16, 0, 0);
        }
        __syncthreads();
        bf16x8 af[2], bfr[4];
        #pragma unroll
        for (int mf = 0; mf < 2; ++mf) {
            int row = wm * 32 + mf * 16 + rl;
            af[mf] = *(const bf16x8*)(As + row * 32 + kg * 8);
        }
        #pragma unroll
        for (int nf = 0; nf < 4; ++nf) {
            int row = wn * 64 + nf * 16 + rl;
            bfr[nf] = *(const bf16x8*)(Bs + row * 32 + kg * 8);
        }
        #pragma unroll
        for (int mf = 0; mf < 2; ++mf)
            #pragma unroll
            for (int nf = 0; nf < 4; ++nf)
                acc[mf][nf] = __builtin_amdgcn_mfma_f32_16x16x32_bf16(af[mf], bfr[nf], acc[mf][nf], 0, 0, 0);
        __syncthreads();
    }

    float* Cb = tcat + (size_t)b * MROWS * HW;
    #pragma unroll
    for (int mf = 0; mf < 2; ++mf) {
        int rowb = m0 + wm * 32 + mf * 16 + kg * 4;
        #pragma unroll
        for (int nf = 0; nf < 4; ++nf) {
            int col = n0 + wn * 64 + nf * 16 + rl;
            #pragma unroll
            for (int i = 0; i < 4; ++i)
                Cb[(size_t)(rowb + i) * HW + col] = acc[mf][nf][i];
        }
    }
}

// ---------------------------------------------------------------- GroupNorm(64 groups of 4ch) + affine + ReLU, in place on t rows
__global__ __launch_bounds__(256) void gn_kernel(
    float* __restrict__ tcat,
    const float* __restrict__ gn_g, const float* __restrict__ gn_b)
{
    int blk = blockIdx.x;            // b*64 + c64
    int b = blk >> 6, c64 = blk & 63;
    float* base = tcat + ((size_t)b * MROWS + c64 * 4) * HW;
    int tid = threadIdx.x;
    float s = 0.f, sq = 0.f;
    for (int i = tid; i < 4096; i += 256) {
        float v = base[i];
        s += v; sq += v * v;
    }
    __shared__ float rs[4], rq[4];
    int lane = tid & 63, wv = tid >> 6;
    #pragma unroll
    for (int off = 32; off; off >>= 1) {
        s  += __shfl_down(s, off);
        sq += __shfl_down(sq, off);
    }
    if (lane == 0) { rs[wv] = s; rq[wv] = sq; }
    __syncthreads();
    if (tid == 0) {
        float ts = rs[0] + rs[1] + rs[2] + rs[3];
        float tq = rq[0] + rq[1] + rq[2] + rq[3];
        float mu = ts * (1.f / 4096.f);
        float var = tq * (1.f / 4096.f) - mu * mu;
        rs[0] = mu;
        rq[0] = rsqrtf(var + 1e-5f);
    }
    __syncthreads();
    float mu = rs[0], inv = rq[0];
    for (int i = tid; i < 4096; i += 256) {
        int cc = i >> 10;            // local channel 0..3
        int ch = c64 * 4 + cc;
        float v = (base[i] - mu) * inv;
        v = v * gn_g[ch] + gn_b[ch];
        base[i] = fmaxf(v, 0.f);
    }
}

// ---------------------------------------------------------------- wmap v2: tiled GEMM
// wmap[(b*4+r), o, hw] = c2_b[o] + sum_c c2_w[o,c] * tcat[b, c*4+r, hw]
#define WO  56   // o-tile (392 = 7*56)
#define WHW 128  // hw-tile
__global__ __launch_bounds__(256) void wmap2_kernel(
    const float* __restrict__ tcat, const float* __restrict__ c2_w,
    const float* __restrict__ c2_b, float* __restrict__ wmap)
{
    __shared__ float ts[C2K][WHW];   // 32 KB
    __shared__ float ws[WO][C2K];    // 14 KB
    int bx = blockIdx.x;             // b*4 + r
    int b = bx >> 2, r = bx & 3;
    int hw0 = blockIdx.y * WHW;
    int o0  = blockIdx.z * WO;
    int tid = threadIdx.x;
    #pragma unroll
    for (int l = 0; l < (C2K * WHW) / 256; ++l) {
        int flat = l * 256 + tid;
        int c = flat >> 7, hw = flat & 127;
        ts[c][hw] = tcat[((size_t)b * MROWS + c * 4 + r) * HW + hw0 + hw];
    }
    for (int flat = tid; flat < WO * C2K; flat += 256) {
        int o = flat >> 6, k = flat & 63;
        ws[o][k] = c2_w[(size_t)(o0 + o) * C2K + k];
    }
    __syncthreads();
    int hwl = tid & 63;
    int oq  = tid >> 6;
    float acc[14][2];
    #pragma unroll
    for (int i = 0; i < 14; ++i) {
        float bv = c2_b[o0 + oq * 14 + i];
        acc[i][0] = bv; acc[i][1] = bv;
    }
    for (int k = 0; k < C2K; ++k) {
        float t0 = ts[k][hwl], t1 = ts[k][hwl + 64];
        #pragma unroll
        for (int i = 0; i < 14; ++i) {
            float wv = ws[oq * 14 + i][k];
            acc[i][0] += wv * t0;
            acc[i][1] += wv * t1;
        }
    }
    float* wb = wmap + (size_t)bx * WMAP_O * HW + hw0;
    #pragma unroll
    for (int i = 0; i < 14; ++i) {
        int o = o0 + oq * 14 + i;
        wb[(size_t)o * HW + hwl]      = acc[i][0];
        wb[(size_t)o * HW + hwl + 64] = acc[i][1];
    }
}

// ---------------------------------------------------------------- aggregation with kernel rotation
__global__ __launch_bounds__(256) void agg_kernel(
    const float* __restrict__ tcat, const float* __restrict__ wmap,
    float* __restrict__ out)
{
    int bx = blockIdx.x;             // b*32 + g*4 + r
    int b = bx >> 5;
    int g = (bx >> 2) & 7;
    int r = bx & 3;
    int h0 = blockIdx.y * 8;
    int tid = threadIdx.x;
    int tw = tid & 31, th = tid >> 5;
    int h = h0 + th, w = tw;

    int A, Bc, Cc;
    if      (r == 0) { A = 0;  Bc = 7;  Cc = 1;  }
    else if (r == 1) { A = 6;  Bc = -1; Cc = 7;  }
    else if (r == 2) { A = 48; Bc = -7; Cc = -1; }
    else             { A = 42; Bc = 1;  Cc = -7; }

    float wr[49];
    const float* wmb = wmap + (size_t)(b * 4 + r) * WMAP_O * HW + h * WWID + w;
    #pragma unroll
    for (int p = 0; p < 49; ++p) {
        int ki = p / 7, kj = p % 7;
        wr[p] = wmb[(size_t)(g * 49 + A + Bc * ki + Cc * kj) * HW];
    }

    __shared__ float vt[14][40];
    const float* vbase = tcat + ((size_t)b * MROWS + 256) * HW;  // v rows
    for (int c = 0; c < GC; ++c) {
        int ch = (g * GC + c) * 4 + r;
        __syncthreads();
        for (int idx = tid; idx < 14 * 38; idx += 256) {
            int row = idx / 38, col = idx % 38;
            int gh = h0 - 3 + row, gw = col - 3;
            float v = 0.f;
            if (gh >= 0 && gh < HH && gw >= 0 && gw < WWID)
                v = vbase[(size_t)ch * HW + gh * WWID + gw];
            vt[row][col] = v;
        }
        __syncthreads();
        float acc = 0.f;
        #pragma unroll
        for (int p = 0; p < 49; ++p)
            acc += wr[p] * vt[th + p / 7][tw + p % 7];
        out[((size_t)b * 512 + ch) * HW + h * WWID + w] = acc;
    }
}

// ---------------------------------------------------------------- launch
extern "C" void kernel_launch(void* const* d_in, const int* in_sizes, int n_in,
                              void* d_out, int out_size, void* d_ws, size_t ws_size,
                              hipStream_t stream)
{
    const float* x    = (const float*)d_in[0];
    const float* v_w  = (const float*)d_in[1];
    const float* c1_w = (const float*)d_in[2];
    const float* gn_g = (const float*)d_in[3];
    const float* gn_b = (const float*)d_in[4];
    const float* c2_w = (const float*)d_in[5];
    const float* c2_b = (const float*)d_in[6];
    float* out = (float*)d_out;

    // workspace layout (XT aliases wmap; XT dead before wmap written):
    short* Wb   = (short*)d_ws;                        // 768*512 bf16      = 0.79 MB
    float* tcat = (float*)(Wb + (size_t)MROWS * KDIM); // 8*768*1024 f32    = 25.2 MB
    float* wmap = tcat + (size_t)BB * MROWS * HW;      // 8*4*392*1024 f32  = 51.4 MB
    short* XT   = (short*)wmap;                        // 8*1024*512 bf16   =  8.4 MB (aliased)

    lift_bf16_kernel<<<(MROWS * KDIM + 255) / 256, 256, 0, stream>>>(v_w, c1_w, Wb);
    xt_kernel       <<<dim3(16, 8, 8), 256, 0, stream>>>(x, XT);
    gemm_mfma_kernel<<<dim3(HW / GBN, MROWS / GBM, BB), 256, 0, stream>>>(Wb, XT, tcat);
    gn_kernel       <<<BB * 64, 256, 0, stream>>>(tcat, gn_g, gn_b);
    wmap2_kernel    <<<dim3(BB * 4, HW / WHW, WMAP_O / WO), 256, 0, stream>>>(tcat, c2_w, c2_b, wmap);
    agg_kernel      <<<dim3(BB * NG * 4, 4), 256, 0, stream>>>(tcat, wmap, out);
}

// Round 4
// 92.983 us; speedup vs baseline: 4.2962x; 1.1674x over previous
//
#include <hip/hip_runtime.h>

// Problem constants
#define BB   8
#define CIN  128
#define COUT 128
#define KS   7
#define HH   32
#define WWID 32
#define HW   1024
#define NG   8     // dynamic-weight groups
#define GC   16    // channels per group
#define MROWS 768  // 256 t-rows + 512 v-rows
#define KDIM 512
#define WMAP_O 392 // 49*8
#define WMAP_OP 448 // padded to 7*64
#define C2K  64

typedef __attribute__((ext_vector_type(8))) short bf16x8;
typedef __attribute__((ext_vector_type(4))) float f32x4;

__device__ __forceinline__ short f2bf(float f) {
    unsigned u = __builtin_bit_cast(unsigned, f);
    u += 0x7fff + ((u >> 16) & 1);   // RNE
    return (short)(u >> 16);
}

// ---------------------------------------------------------------- lift (bf16 out)
__global__ __launch_bounds__(256) void lift_bf16_kernel(
    const float* __restrict__ v_w, const float* __restrict__ c1_w,
    short* __restrict__ Wb)
{
    int idx = blockIdx.x * 256 + threadIdx.x;
    if (idx >= MROWS * KDIM) return;
    int row = idx >> 9;          // /512
    int col = idx & 511;
    int i = col >> 2, s = col & 3;
    float val;
    if (row < 256) {
        int o = row >> 2, r = row & 3;
        val = c1_w[(o * CIN + i) * 4 + ((s - r) & 3)];
    } else {
        int ro = row - 256;
        int o = ro >> 2, r = ro & 3;
        val = v_w[(o * CIN + i) * 4 + ((s - r) & 3)];
    }
    Wb[idx] = f2bf(val);
}

// ---------------------------------------------------------------- c2 prep: pad to 448 rows, bf16
__global__ __launch_bounds__(256) void c2prep_kernel(
    const float* __restrict__ c2_w, const float* __restrict__ c2_b,
    short* __restrict__ c2wb, float* __restrict__ c2bp)
{
    int idx = blockIdx.x * 256 + threadIdx.x;
    if (idx < WMAP_OP * C2K) {
        int o = idx >> 6, k = idx & 63;
        c2wb[idx] = f2bf(o < WMAP_O ? c2_w[o * C2K + k] : 0.f);
    }
    if (idx < WMAP_OP)
        c2bp[idx] = idx < WMAP_O ? c2_b[idx] : 0.f;
}

// ---------------------------------------------------------------- transpose x -> XT bf16 [b][hw][c]
__global__ __launch_bounds__(256) void xt_kernel(
    const float* __restrict__ x, short* __restrict__ XT)
{
    __shared__ short t[64][66];
    int b = blockIdx.z, c0 = blockIdx.y * 64, n0 = blockIdx.x * 64;
    int tid = threadIdx.x;
    const float* xb = x + ((size_t)b * KDIM + c0) * HW + n0;
    #pragma unroll
    for (int l = 0; l < 16; ++l) {
        int flat = l * 256 + tid;
        int row = flat >> 6, col = flat & 63;   // row=c_local, col=n_local
        t[col][row] = f2bf(xb[(size_t)row * HW + col]);
    }
    __syncthreads();
    short* xt = XT + ((size_t)b * HW + n0) * KDIM + c0;
    #pragma unroll
    for (int l = 0; l < 8; ++l) {
        int u = l * 256 + tid;
        int nrow = u >> 5, cp = (u & 31) * 2;
        short2 v = make_short2(t[nrow][cp], t[nrow][cp + 1]);
        *(short2*)(xt + (size_t)nrow * KDIM + cp) = v;
    }
}

// ---------------------------------------------------------------- MFMA GEMM: tcat[b] = Wb @ X[b]
// A = Wb [768][512] bf16, B^T = XT [b][1024][512] bf16, C = tcat fp32
// LDS k-chunk XOR swizzle: kc' = kc ^ ((row>>1)&3)  (4 chunks/row)
#define GBM 64
#define GBN 128
__global__ __launch_bounds__(256) void gemm_mfma_kernel(
    const short* __restrict__ Wb, const short* __restrict__ XT,
    float* __restrict__ tcat)
{
    __shared__ short As[GBM * 32];   // 4 KB
    __shared__ short Bs[GBN * 32];   // 8 KB
    int b  = blockIdx.z;
    int m0 = blockIdx.y * GBM;
    int n0 = blockIdx.x * GBN;
    int tid = threadIdx.x;
    int lane = tid & 63, wv = tid >> 6;
    int wm = wv & 1, wn = wv >> 1;          // wave tile: 32 rows x 64 cols
    int rl = lane & 15, kg = lane >> 4;
    const short* Ab = Wb + (size_t)m0 * KDIM;
    const short* Bb = XT + ((size_t)b * HW + n0) * KDIM;
    f32x4 acc[2][4] = {};

    for (int k0 = 0; k0 < KDIM; k0 += 32) {
        // stage A: 64 rows x 4 chunks(16B), swizzled source
        {
            int c = tid;
            int row = c >> 2, kc = c & 3;
            int kcs = kc ^ ((row >> 1) & 3);
            __builtin_amdgcn_global_load_lds(
                (const __attribute__((address_space(1))) void*)(Ab + (size_t)row * KDIM + k0 + kcs * 8),
                (__attribute__((address_space(3))) void*)(As + wv * 512),
                16, 0, 0);
        }
        // stage B: 128 rows x 4 chunks, swizzled source
        #pragma unroll
        for (int l = 0; l < 2; ++l) {
            int c = l * 256 + tid;
            int row = c >> 2, kc = c & 3;
            int kcs = kc ^ ((row >> 1) & 3);
            __builtin_amdgcn_global_load_lds(
                (const __attribute__((address_space(1))) void*)(Bb + (size_t)row * KDIM + k0 + kcs * 8),
                (__attribute__((address_space(3))) void*)(Bs + (l * 256 + wv * 64) * 8),
                16, 0, 0);
        }
        __syncthreads();
        bf16x8 af[2], bfr[4];
        #pragma unroll
        for (int mf = 0; mf < 2; ++mf) {
            int row = wm * 32 + mf * 16 + rl;
            af[mf] = *(const bf16x8*)(As + row * 32 + (kg ^ ((row >> 1) & 3)) * 8);
        }
        #pragma unroll
        for (int nf = 0; nf < 4; ++nf) {
            int row = wn * 64 + nf * 16 + rl;
            bfr[nf] = *(const bf16x8*)(Bs + row * 32 + (kg ^ ((row >> 1) & 3)) * 8);
        }
        #pragma unroll
        for (int mf = 0; mf < 2; ++mf)
            #pragma unroll
            for (int nf = 0; nf < 4; ++nf)
                acc[mf][nf] = __builtin_amdgcn_mfma_f32_16x16x32_bf16(af[mf], bfr[nf], acc[mf][nf], 0, 0, 0);
        __syncthreads();
    }

    float* Cb = tcat + (size_t)b * MROWS * HW;
    #pragma unroll
    for (int mf = 0; mf < 2; ++mf) {
        int rowb = m0 + wm * 32 + mf * 16 + kg * 4;
        #pragma unroll
        for (int nf = 0; nf < 4; ++nf) {
            int col = n0 + wn * 64 + nf * 16 + rl;
            #pragma unroll
            for (int i = 0; i < 4; ++i)
                Cb[(size_t)(rowb + i) * HW + col] = acc[mf][nf][i];
        }
    }
}

// ---------------------------------------------------------------- GroupNorm(64 groups of 4ch) + affine + ReLU, in place on t rows
__global__ __launch_bounds__(256) void gn_kernel(
    float* __restrict__ tcat,
    const float* __restrict__ gn_g, const float* __restrict__ gn_b)
{
    int blk = blockIdx.x;            // b*64 + c64
    int b = blk >> 6, c64 = blk & 63;
    float* base = tcat + ((size_t)b * MROWS + c64 * 4) * HW;
    int tid = threadIdx.x;
    float s = 0.f, sq = 0.f;
    for (int i = tid; i < 4096; i += 256) {
        float v = base[i];
        s += v; sq += v * v;
    }
    __shared__ float rs[4], rq[4];
    int lane = tid & 63, wv = tid >> 6;
    #pragma unroll
    for (int off = 32; off; off >>= 1) {
        s  += __shfl_down(s, off);
        sq += __shfl_down(sq, off);
    }
    if (lane == 0) { rs[wv] = s; rq[wv] = sq; }
    __syncthreads();
    if (tid == 0) {
        float ts = rs[0] + rs[1] + rs[2] + rs[3];
        float tq = rq[0] + rq[1] + rq[2] + rq[3];
        float mu = ts * (1.f / 4096.f);
        float var = tq * (1.f / 4096.f) - mu * mu;
        rs[0] = mu;
        rq[0] = rsqrtf(var + 1e-5f);
    }
    __syncthreads();
    float mu = rs[0], inv = rq[0];
    for (int i = tid; i < 4096; i += 256) {
        int cc = i >> 10;            // local channel 0..3
        int ch = c64 * 4 + cc;
        float v = (base[i] - mu) * inv;
        v = v * gn_g[ch] + gn_b[ch];
        base[i] = fmaxf(v, 0.f);
    }
}

// ---------------------------------------------------------------- transpose normalized t -> tn bf16 [b4r][hw][c64]
__global__ __launch_bounds__(256) void tkn_kernel(
    const float* __restrict__ tcat, short* __restrict__ tn)
{
    __shared__ short ts[64][72];
    int b4r = blockIdx.x;
    int b = b4r >> 2, r = b4r & 3;
    int hw0 = blockIdx.y * 64;
    int tid = threadIdx.x;
    #pragma unroll
    for (int l = 0; l < 16; ++l) {
        int flat = l * 256 + tid;
        int c = flat >> 6, hw = flat & 63;
        ts[c][hw] = f2bf(tcat[((size_t)b * MROWS + c * 4 + r) * HW + hw0 + hw]);
    }
    __syncthreads();
    #pragma unroll
    for (int l = 0; l < 2; ++l) {
        int u = l * 256 + tid;
        int hw = u >> 3, c0 = (u & 7) * 8;
        bf16x8 v;
        #pragma unroll
        for (int j = 0; j < 8; ++j) v[j] = ts[c0 + j][hw];
        *(bf16x8*)(tn + ((size_t)b4r * HW + hw0 + hw) * C2K + c0) = v;
    }
}

// ---------------------------------------------------------------- wmap v3: MFMA GEMM
// wmapP[b4r][o][hw] = c2bp[o] + sum_c c2wb[o][c] * tn[b4r][hw][c]
// M=448 (o, 64-tiles), N=1024 (hw, 128-tiles), K=64 staged once.
// LDS k-chunk swizzle: kc' = kc ^ (row&7)  (8 chunks/row)
__global__ __launch_bounds__(256) void wmap3_kernel(
    const short* __restrict__ c2wb, const short* __restrict__ tn,
    const float* __restrict__ c2bp, float* __restrict__ wmapP)
{
    __shared__ short As[64 * 64];    // 8 KB
    __shared__ short Bs[128 * 64];   // 16 KB
    int n0  = blockIdx.x * 128;
    int m0  = blockIdx.y * 64;
    int b4r = blockIdx.z;
    int tid = threadIdx.x;
    int lane = tid & 63, wv = tid >> 6;
    int wm = wv & 1, wn = wv >> 1;
    int rl = lane & 15, kg = lane >> 4;
    const short* Bb = tn + ((size_t)b4r * HW + n0) * C2K;

    // stage A: 64 rows x 8 chunks = 512 chunks
    #pragma unroll
    for (int l = 0; l < 2; ++l) {
        int c = l * 256 + tid;
        int row = c >> 3, kc = c & 7;
        int kcs = kc ^ (row & 7);
        __builtin_amdgcn_global_load_lds(
            (const __attribute__((address_space(1))) void*)(c2wb + (size_t)(m0 + row) * C2K + kcs * 8),
            (__attribute__((address_space(3))) void*)(As + (l * 256 + wv * 64) * 8),
            16, 0, 0);
    }
    // stage B: 128 rows x 8 chunks = 1024 chunks
    #pragma unroll
    for (int l = 0; l < 4; ++l) {
        int c = l * 256 + tid;
        int row = c >> 3, kc = c & 7;
        int kcs = kc ^ (row & 7);
        __builtin_amdgcn_global_load_lds(
            (const __attribute__((address_space(1))) void*)(Bb + (size_t)row * C2K + kcs * 8),
            (__attribute__((address_space(3))) void*)(Bs + (l * 256 + wv * 64) * 8),
            16, 0, 0);
    }
    __syncthreads();

    f32x4 acc[2][4] = {};
    #pragma unroll
    for (int ks = 0; ks < 2; ++ks) {
        bf16x8 af[2], bfr[4];
        #pragma unroll
        for (int mf = 0; mf < 2; ++mf) {
            int row = wm * 32 + mf * 16 + rl;
            af[mf] = *(const bf16x8*)(As + row * 64 + ((ks * 4 + kg) ^ (row & 7)) * 8);
        }
        #pragma unroll
        for (int nf = 0; nf < 4; ++nf) {
            int row = wn * 64 + nf * 16 + rl;
            bfr[nf] = *(const bf16x8*)(Bs + row * 64 + ((ks * 4 + kg) ^ (row & 7)) * 8);
        }
        #pragma unroll
        for (int mf = 0; mf < 2; ++mf)
            #pragma unroll
            for (int nf = 0; nf < 4; ++nf)
                acc[mf][nf] = __builtin_amdgcn_mfma_f32_16x16x32_bf16(af[mf], bfr[nf], acc[mf][nf], 0, 0, 0);
    }

    float* wb = wmapP + (size_t)b4r * WMAP_OP * HW;
    #pragma unroll
    for (int mf = 0; mf < 2; ++mf) {
        int rowb = m0 + wm * 32 + mf * 16 + kg * 4;
        float bi[4];
        #pragma unroll
        for (int i = 0; i < 4; ++i) bi[i] = c2bp[rowb + i];
        #pragma unroll
        for (int nf = 0; nf < 4; ++nf) {
            int col = n0 + wn * 64 + nf * 16 + rl;
            #pragma unroll
            for (int i = 0; i < 4; ++i)
                wb[(size_t)(rowb + i) * HW + col] = acc[mf][nf][i] + bi[i];
        }
    }
}

// ---------------------------------------------------------------- aggregation with kernel rotation
__global__ __launch_bounds__(256) void agg_kernel(
    const float* __restrict__ tcat, const float* __restrict__ wmap,
    float* __restrict__ out)
{
    int bx = blockIdx.x;             // b*32 + g*4 + r
    int b = bx >> 5;
    int g = (bx >> 2) & 7;
    int r = bx & 3;
    int h0 = blockIdx.y * 8;
    int tid = threadIdx.x;
    int tw = tid & 31, th = tid >> 5;
    int h = h0 + th, w = tw;

    int A, Bc, Cc;
    if      (r == 0) { A = 0;  Bc = 7;  Cc = 1;  }
    else if (r == 1) { A = 6;  Bc = -1; Cc = 7;  }
    else if (r == 2) { A = 48; Bc = -7; Cc = -1; }
    else             { A = 42; Bc = 1;  Cc = -7; }

    float wr[49];
    const float* wmb = wmap + (size_t)(b * 4 + r) * WMAP_OP * HW + h * WWID + w;
    #pragma unroll
    for (int p = 0; p < 49; ++p) {
        int ki = p / 7, kj = p % 7;
        wr[p] = wmb[(size_t)(g * 49 + A + Bc * ki + Cc * kj) * HW];
    }

    __shared__ float vt[14][40];
    const float* vbase = tcat + ((size_t)b * MROWS + 256) * HW;  // v rows
    for (int c = 0; c < GC; ++c) {
        int ch = (g * GC + c) * 4 + r;
        __syncthreads();
        for (int idx = tid; idx < 14 * 38; idx += 256) {
            int row = idx / 38, col = idx % 38;
            int gh = h0 - 3 + row, gw = col - 3;
            float v = 0.f;
            if (gh >= 0 && gh < HH && gw >= 0 && gw < WWID)
                v = vbase[(size_t)ch * HW + gh * WWID + gw];
            vt[row][col] = v;
        }
        __syncthreads();
        float acc = 0.f;
        #pragma unroll
        for (int p = 0; p < 49; ++p)
            acc += wr[p] * vt[th + p / 7][tw + p % 7];
        out[((size_t)b * 512 + ch) * HW + h * WWID + w] = acc;
    }
}

// ---------------------------------------------------------------- launch
extern "C" void kernel_launch(void* const* d_in, const int* in_sizes, int n_in,
                              void* d_out, int out_size, void* d_ws, size_t ws_size,
                              hipStream_t stream)
{
    const float* x    = (const float*)d_in[0];
    const float* v_w  = (const float*)d_in[1];
    const float* c1_w = (const float*)d_in[2];
    const float* gn_g = (const float*)d_in[3];
    const float* gn_b = (const float*)d_in[4];
    const float* c2_w = (const float*)d_in[5];
    const float* c2_b = (const float*)d_in[6];
    float* out = (float*)d_out;

    // workspace layout (XT aliases wmapP; XT dead before wmapP written)
    char* p = (char*)d_ws;
    short* Wb    = (short*)p;            p += (size_t)MROWS * KDIM * 2;        // 0.79 MB
    float* tcat  = (float*)p;            p += (size_t)BB * MROWS * HW * 4;     // 25.2 MB
    float* wmapP = (float*)p;            p += (size_t)32 * WMAP_OP * HW * 4;   // 58.7 MB
    short* XT    = (short*)wmapP;                                              // 8.4 MB (aliased)
    short* tn    = (short*)p;            p += (size_t)32 * HW * C2K * 2;       // 4.2 MB
    short* c2wb  = (short*)p;            p += (size_t)WMAP_OP * C2K * 2;       // 57 KB
    float* c2bp  = (float*)p;            p += (size_t)WMAP_OP * 4;

    c2prep_kernel   <<<(WMAP_OP * C2K + 255) / 256, 256, 0, stream>>>(c2_w, c2_b, c2wb, c2bp);
    lift_bf16_kernel<<<(MROWS * KDIM + 255) / 256, 256, 0, stream>>>(v_w, c1_w, Wb);
    xt_kernel       <<<dim3(16, 8, 8), 256, 0, stream>>>(x, XT);
    gemm_mfma_kernel<<<dim3(HW / GBN, MROWS / GBM, BB), 256, 0, stream>>>(Wb, XT, tcat);
    gn_kernel       <<<BB * 64, 256, 0, stream>>>(tcat, gn_g, gn_b);
    tkn_kernel      <<<dim3(32, 16), 256, 0, stream>>>(tcat, tn);
    wmap3_kernel    <<<dim3(HW / 128, WMAP_OP / 64, 32), 256, 0, stream>>>(c2wb, tn, c2bp, wmapP);
    agg_kernel      <<<dim3(BB * NG * 4, 4), 256, 0, stream>>>(tcat, wmapP, out);
}